// Round 14
// baseline (27.135 us; speedup 1.0000x reference)
//
#include <hip/hip_runtime.h>

#define TI 64     // tile edge
#define BT 256    // threads per pairs block (4 waves)

// bell(d,s) = 2*max(0,1-r)^2 - max(0,1-2r)^2,  r = d/s  (branchless identity;
// r<=1/2 -> 1-2r^2, 1/2<r<=1 -> 2(1-r)^2, r>1 -> 0).  Sentinel pairs produce
// r = NaN or inf; v_max_f32's IEEE maxNum semantics turn both into 0.
__device__ __forceinline__ float bell(float d, float s) {
    float r  = fabsf(d) * __builtin_amdgcn_rcpf(s);  // abs folds as modifier
    float u  = fmaxf(1.0f - r, 0.0f);
    float v  = fmaxf(fmaf(-2.0f, r, 1.0f), 0.0f);
    float uu = u * u;
    return fmaf(u, u, uu) - v * v;                   // 2u^2 - v^2
}

__device__ __forceinline__ int tri_off(int ti, int T) {
    return ti * T - (ti * (ti - 1)) / 2;    // first block index of tile-row ti
}

__global__ __launch_bounds__(256) void prep_kernel(
    const float* __restrict__ pos,
    const float* __restrict__ msx, const float* __restrict__ msy,
    const float* __restrict__ bpx, const float* __restrict__ bpy,
    const int*   __restrict__ midx,
    int num_nodes, int m, int N, int Npad,
    float4* __restrict__ p4, float* __restrict__ t_part)
{
    const int i = blockIdx.x * 256 + threadIdx.x;
    // macro_idx is int64 in the reference; sorted => idx[1] >= 1, so the odd
    // int32 words are all zero iff the buffer is little-endian int64.
    const bool is64 = (midx[1] == 0) && (midx[3] == 0) && (midx[5] == 0);
    float a = 0.0f, xi = 1e18f, yi = 1e18f, hx = 0.0f, hy = 0.0f;
    if (i < N) {
        hx = 0.5f * msx[i];
        hy = 0.5f * msy[i];
        if (i < m) {
            int id = is64 ? midx[2 * i] : midx[i];
            xi = pos[id]             + hx;
            yi = pos[num_nodes + id] + hy;
        } else {
            xi = bpx[i - m];
            yi = bpy[i - m];
        }
        a = 4.0f * hx * hy;                 // true area
    }
    if (i < Npad) p4[i] = make_float4(xi, yi, hx, hy);

    for (int off = 32; off > 0; off >>= 1) a += __shfl_down(a, off, 64);
    __shared__ float wpart[4];
    const int lane = threadIdx.x & 63, wid = threadIdx.x >> 6;
    if (lane == 0) wpart[wid] = a;
    __syncthreads();
    if (threadIdx.x == 0)
        t_part[blockIdx.x] = wpart[0] + wpart[1] + wpart[2] + wpart[3];
}

__global__ __launch_bounds__(BT) void pairs_kernel(
    const float4* __restrict__ p4, int T, float* __restrict__ partials)
{
    // decode linear block id -> (ti, tj), ti <= tj
    const int b = blockIdx.x;
    const int w2 = 2 * T + 1;
    int ti = (int)(((float)w2 - sqrtf((float)(w2 * w2 - 8 * b))) * 0.5f);
    if (ti > T - 1) ti = T - 1;
    while (ti > 0 && tri_off(ti, T) > b) --ti;
    while (tri_off(ti + 1, T) <= b) ++ti;
    const int tj = ti + (b - tri_off(ti, T));

    __shared__ float4 qs[TI];
    __shared__ float  qa[TI];               // quarter-area of j-nodes
    if (threadIdx.x < TI) {
        float4 q = p4[tj * TI + threadIdx.x];
        qs[threadIdx.x] = q;
        qa[threadIdx.x] = q.z * q.w;
    }
    __syncthreads();

    const int lane = threadIdx.x & 63, wid = threadIdx.x >> 6;
    const float4 P = p4[ti * TI + lane];    // coalesced, L2-hot
    const float pai = P.z * P.w;            // quarter-area of node i

    float a0 = 0.0f, a1 = 0.0f;
    #pragma unroll
    for (int k = 0; k < 16; k += 2) {
        {
            const float4 q = qs[wid * 16 + k];
            float px = bell(P.x - q.x, P.z + q.z);
            float py = bell(P.y - q.y, P.w + q.w);
            a0 = fmaf((pai + qa[wid * 16 + k]) * px, py, a0);
        }
        {
            const float4 q = qs[wid * 16 + k + 1];
            float px = bell(P.x - q.x, P.z + q.z);
            float py = bell(P.y - q.y, P.w + q.w);
            a1 = fmaf((pai + qa[wid * 16 + k + 1]) * px, py, a1);
        }
    }
    float part = a0 + a1;
    if (ti == tj) part *= 0.5f;             // diag tiles half-weight

    for (int off = 32; off > 0; off >>= 1) part += __shfl_down(part, off, 64);
    if (lane == 0) partials[b * 4 + wid] = part;   // per-wave partial, no sync
}

__global__ __launch_bounds__(256) void fin_kernel(
    const float* __restrict__ partials, int np,
    const float* __restrict__ t_part, int nt, float* __restrict__ out)
{
    float s = 0.0f;
    for (int i = threadIdx.x; i < np; i += 256) s += partials[i];
    float t = 0.0f;
    for (int i = threadIdx.x; i < nt; i += 256) t += t_part[i];
    for (int off = 32; off > 0; off >>= 1) {
        s += __shfl_down(s, off, 64);
        t += __shfl_down(t, off, 64);
    }
    __shared__ float ws[4], wt[4];
    const int lane = threadIdx.x & 63, wid = threadIdx.x >> 6;
    if (lane == 0) { ws[wid] = s; wt[wid] = t; }
    __syncthreads();
    if (threadIdx.x == 0) {
        float S = ws[0] + ws[1] + ws[2] + ws[3];
        float T = wt[0] + wt[1] + wt[2] + wt[3];
        // quarter-area scale, half-counted: triu = 4*S - T
        float l = (4.0f * S - T) / T;
        out[0] = l * l;
    }
}

extern "C" void kernel_launch(void* const* d_in, const int* in_sizes, int n_in,
                              void* d_out, int out_size, void* d_ws, size_t ws_size,
                              hipStream_t stream) {
    const float* pos = (const float*)d_in[0];
    const float* msx = (const float*)d_in[1];
    const float* msy = (const float*)d_in[2];
    const float* bpx = (const float*)d_in[3];
    const float* bpy = (const float*)d_in[4];
    const int*  midx = (const int*)d_in[5];

    const int num_nodes = in_sizes[0] / 2;
    const int m  = in_sizes[5];          // 4000 movable macros
    const int nb = in_sizes[3];          // 252 boundary nodes
    const int N  = m + nb;

    const int T     = (N + TI - 1) / TI;     // 68 tiles
    const int Npad  = T * TI;                // 4352
    const int nblk  = T * (T + 1) / 2;       // 2346 tile-pairs
    const int nprep = (Npad + 255) / 256;    // 17

    float4* p4       = (float4*)d_ws;
    float*  t_part   = (float*)(p4 + Npad);
    float*  partials = t_part + nprep;       // 4 * nblk floats

    prep_kernel<<<nprep, 256, 0, stream>>>(pos, msx, msy, bpx, bpy, midx,
                                           num_nodes, m, N, Npad, p4, t_part);

    pairs_kernel<<<nblk, BT, 0, stream>>>(p4, T, partials);

    fin_kernel<<<1, 256, 0, stream>>>(partials, 4 * nblk, t_part, nprep,
                                      (float*)d_out);
}

// Round 15
// 16.337 us; speedup vs baseline: 1.6609x; 1.6609x over previous
//
#include <hip/hip_runtime.h>

#define TI 64     // tile edge
#define BT 256    // threads per block (4 waves)

// bell(d,s) = 2*max(0,1-r)^2 - max(0,1-2r)^2,  r = |d|/s  (branchless;
// r<=1/2 -> 1-2r^2, 1/2<r<=1 -> 2(1-r)^2, r>1 -> 0). Sentinel pairs give
// r = NaN/inf; v_max_f32 IEEE maxNum semantics turn both into 0. (HW-validated R14.)
__device__ __forceinline__ float bell(float d, float s) {
    float r  = fabsf(d) * __builtin_amdgcn_rcpf(s);
    float u  = fmaxf(1.0f - r, 0.0f);
    float v  = fmaxf(fmaf(-2.0f, r, 1.0f), 0.0f);
    float uu = u * u;
    return fmaf(u, u, uu) - v * v;                   // 2u^2 - v^2
}

__device__ __forceinline__ int tri_off(int ti, int T) {
    return ti * T - (ti * (ti - 1)) / 2;    // first block index of tile-row ti
}

// prep one node g -> (x_center, y_center, hx, hy); sentinel if g >= N
__device__ __forceinline__ float4 prep_node(
    int g, int N, int m, int num_nodes, bool is64,
    const float* __restrict__ pos,
    const float* __restrict__ msx, const float* __restrict__ msy,
    const float* __restrict__ bpx, const float* __restrict__ bpy,
    const int*   __restrict__ midx)
{
    float xi = 1e18f, yi = 1e18f, hx = 0.0f, hy = 0.0f;
    if (g < N) {
        hx = 0.5f * msx[g];
        hy = 0.5f * msy[g];
        if (g < m) {
            int id = is64 ? midx[2 * g] : midx[g];
            xi = pos[id]             + hx;
            yi = pos[num_nodes + id] + hy;
        } else {
            xi = bpx[g - m];
            yi = bpy[g - m];
        }
    }
    return make_float4(xi, yi, hx, hy);
}

__global__ __launch_bounds__(BT) void pairs_kernel(
    const float* __restrict__ pos,
    const float* __restrict__ msx, const float* __restrict__ msy,
    const float* __restrict__ bpx, const float* __restrict__ bpy,
    const int*   __restrict__ midx,
    int num_nodes, int m, int N, int T,
    float* __restrict__ partials, float* __restrict__ t_part)
{
    const int tid = threadIdx.x, lane = tid & 63, wid = tid >> 6;

    // decode linear block id -> (ti, tj), ti <= tj
    const int b = blockIdx.x;
    const int w2 = 2 * T + 1;
    int ti = (int)(((float)w2 - sqrtf((float)(w2 * w2 - 8 * b))) * 0.5f);
    if (ti > T - 1) ti = T - 1;
    while (ti > 0 && tri_off(ti, T) > b) --ti;
    while (tri_off(ti + 1, T) <= b) ++ti;
    const int tj = ti + (b - tri_off(ti, T));

    // ---- in-block gather of both tiles (waves 0 and 1) ----
    __shared__ float4 qs[TI]; __shared__ float qa[TI];
    __shared__ float4 ps[TI]; __shared__ float pa[TI];
    // macro_idx is int64 in the reference; sorted => idx[1] >= 1, so the odd
    // int32 words are all zero iff the buffer is little-endian int64.
    const bool is64 = (midx[1] == 0) && (midx[3] == 0) && (midx[5] == 0);
    if (tid < TI) {                         // wave 0: j-tile
        float4 q = prep_node(tj * TI + tid, N, m, num_nodes, is64,
                             pos, msx, msy, bpx, bpy, midx);
        qs[tid] = q; qa[tid] = q.z * q.w;
    } else if (tid < 2 * TI) {              // wave 1: i-tile
        float4 p = prep_node(ti * TI + (tid - TI), N, m, num_nodes, is64,
                             pos, msx, msy, bpx, bpy, midx);
        ps[tid - TI] = p; pa[tid - TI] = p.z * p.w;
        if (ti == tj) {                     // diag block owns t_part[ti]
            float a = 4.0f * p.z * p.w;     // true area (sentinel -> 0)
            for (int off = 32; off > 0; off >>= 1)
                a += __shfl_down(a, off, 64);
            if (tid == TI) t_part[ti] = a;  // single writer, no atomic
        }
    }
    __syncthreads();

    const float4 P  = ps[lane];
    const float pai = pa[lane];             // quarter-area of node i

    float a0 = 0.0f, a1 = 0.0f;
    #pragma unroll
    for (int k = 0; k < 16; k += 2) {
        {
            const float4 q = qs[wid * 16 + k];
            float px = bell(P.x - q.x, P.z + q.z);
            float py = bell(P.y - q.y, P.w + q.w);
            a0 = fmaf((pai + qa[wid * 16 + k]) * px, py, a0);
        }
        {
            const float4 q = qs[wid * 16 + k + 1];
            float px = bell(P.x - q.x, P.z + q.z);
            float py = bell(P.y - q.y, P.w + q.w);
            a1 = fmaf((pai + qa[wid * 16 + k + 1]) * px, py, a1);
        }
    }
    float part = a0 + a1;
    if (ti == tj) part *= 0.5f;             // diag tiles half-weight

    for (int off = 32; off > 0; off >>= 1) part += __shfl_down(part, off, 64);
    __shared__ float wsum[BT / 64];
    if (lane == 0) wsum[wid] = part;
    __syncthreads();
    if (tid == 0)
        partials[b] = wsum[0] + wsum[1] + wsum[2] + wsum[3];  // one float/block
}

__global__ __launch_bounds__(1024) void fin_kernel(
    const float* __restrict__ partials, int np,
    const float* __restrict__ t_part, int nt, float* __restrict__ out)
{
    float s = 0.0f;
    for (int i = threadIdx.x; i < np; i += 1024) s += partials[i];
    float t = 0.0f;
    for (int i = threadIdx.x; i < nt; i += 1024) t += t_part[i];
    for (int off = 32; off > 0; off >>= 1) {
        s += __shfl_down(s, off, 64);
        t += __shfl_down(t, off, 64);
    }
    __shared__ float ws[16], wt[16];
    const int lane = threadIdx.x & 63, wid = threadIdx.x >> 6;
    if (lane == 0) { ws[wid] = s; wt[wid] = t; }
    __syncthreads();
    if (threadIdx.x == 0) {
        float S = 0.0f, T = 0.0f;
        #pragma unroll
        for (int w = 0; w < 16; ++w) { S += ws[w]; T += wt[w]; }
        // quarter-area scale, diag half-counted: triu = 4*S - T
        float l = (4.0f * S - T) / T;
        out[0] = l * l;
    }
}

extern "C" void kernel_launch(void* const* d_in, const int* in_sizes, int n_in,
                              void* d_out, int out_size, void* d_ws, size_t ws_size,
                              hipStream_t stream) {
    const float* pos = (const float*)d_in[0];
    const float* msx = (const float*)d_in[1];
    const float* msy = (const float*)d_in[2];
    const float* bpx = (const float*)d_in[3];
    const float* bpy = (const float*)d_in[4];
    const int*  midx = (const int*)d_in[5];

    const int num_nodes = in_sizes[0] / 2;
    const int m  = in_sizes[5];          // 4000 movable macros
    const int nb = in_sizes[3];          // 252 boundary nodes
    const int N  = m + nb;

    const int T    = (N + TI - 1) / TI;      // 68 tiles
    const int nblk = T * (T + 1) / 2;        // 2346 tile-pairs

    float* partials = (float*)d_ws;          // nblk floats
    float* t_part   = partials + nblk;       // T floats

    pairs_kernel<<<nblk, BT, 0, stream>>>(pos, msx, msy, bpx, bpy, midx,
                                          num_nodes, m, N, T,
                                          partials, t_part);

    fin_kernel<<<1, 1024, 0, stream>>>(partials, nblk, t_part, T,
                                       (float*)d_out);
}